// Round 10
// baseline (180.304 us; speedup 1.0000x reference)
//
#include <hip/hip_runtime.h>
#include <hip/hip_bf16.h>
#include <stdint.h>

#define IN_SZ   256
#define OUT_SZ  256
#define RANK    60
#define NSEL    256
#define BATCH   1024
#define WELEMS  (IN_SZ * OUT_SZ)   // 65536 elems per channel

typedef __attribute__((ext_vector_type(8))) short          short8;
typedef __attribute__((ext_vector_type(4))) float          f32x4;

static __device__ __forceinline__ unsigned short f32_to_bf16(float f) {
    union { float f; uint32_t u; } c; c.f = f;
    uint32_t u = c.u;
    u += 0x7fffu + ((u >> 16) & 1u);   // RNE
    return (unsigned short)(u >> 16);
}

// pair-packed RNE convert — compiler emits v_cvt_pk_bf16_f32 (same rounding)
static __device__ __forceinline__ short8 cvt8(f32x4 lo, f32x4 hi) {
    union { short8 s; __hip_bfloat162 h[4]; } u;
    u.h[0] = __float22bfloat162_rn(make_float2(lo[0], lo[1]));
    u.h[1] = __float22bfloat162_rn(make_float2(lo[2], lo[3]));
    u.h[2] = __float22bfloat162_rn(make_float2(hi[0], hi[1]));
    u.h[3] = __float22bfloat162_rn(make_float2(hi[2], hi[3]));
    return u.s;
}

// -----------------------------------------------------------------------------
// Kernel 1: W_sel = U[idx] @ V -> bf16 in B-FRAGMENT-MAJOR layout:
//   wt[n][(i>>3)*2048 + o*8 + (i&7)]
// (unchanged — verified correct, ~24 µs)
// -----------------------------------------------------------------------------
__global__ __launch_bounds__(256) void synth_w(
    const float* __restrict__ U, const float* __restrict__ V,
    const int* __restrict__ idx, unsigned short* __restrict__ wt)
{
    __shared__ unsigned short Cs[16][2064];

    int bid = blockIdx.x;                  // 512 blocks
    int L   = (bid & 7) * 64 + (bid >> 3); // XCD swizzle: same-ic -> same XCD
    int ic  = L >> 4;
    int g16 = L & 15;

    int tid = threadIdx.x, lane = tid & 63, wv = tid >> 6;

    int arow = lane & 15;
    int c    = idx[g16 * 16 + arow];
    short8 afr[2];
    #pragma unroll
    for (int ks = 0; ks < 2; ++ks) {
        short8 h;
        #pragma unroll
        for (int j = 0; j < 8; ++j) {
            int r = ks * 32 + (lane >> 4) * 8 + j;
            float u = (r < RANK) ? U[c * RANK + r] : 0.f;
            h[j] = (short)f32_to_bf16(u);
        }
        afr[ks] = h;
    }

    const float* Vb = V + (size_t)ic * 2048;
    #pragma unroll 2
    for (int mt = 0; mt < 32; ++mt) {
        int mloc = (wv * 32 + mt) * 16 + (lane & 15);
        f32x4 acc = {};
        #pragma unroll
        for (int ks = 0; ks < 2; ++ks) {
            short8 b;
            #pragma unroll
            for (int j = 0; j < 8; ++j) {
                int r = ks * 32 + (lane >> 4) * 8 + j;
                float v = (r < RANK) ? Vb[(size_t)r * WELEMS + mloc] : 0.f;
                b[j] = (short)f32_to_bf16(v);
            }
            acc = __builtin_amdgcn_mfma_f32_16x16x32_bf16(afr[ks], b, acc, 0, 0, 0);
        }
        #pragma unroll
        for (int j = 0; j < 4; ++j) {
            int nl = (lane >> 4) * 4 + j;
            Cs[nl][wv * 512 + mt * 16 + (lane & 15)] = f32_to_bf16(acc[j]);
        }
    }
    __syncthreads();

    #pragma unroll
    for (int t0 = 0; t0 < 16; ++t0) {
        int t  = t0 * 256 + tid;
        int nl = t >> 8;
        int o  = t & 255;
        short8 h;
        #pragma unroll
        for (int il = 0; il < 8; ++il) h[il] = (short)Cs[nl][il * 256 + o];
        int n = g16 * 16 + nl;
        size_t base = (size_t)n * WELEMS + (size_t)ic * 2048 + (size_t)o * 8;
        *reinterpret_cast<short8*>(wt + base) = h;
    }
}

// -----------------------------------------------------------------------------
// Kernel 2: out[n] = x[n] @ W_sel[n] + bias[idx[n]]
// R8 skeleton + L2-thrash fix:
//  - x staging loads and out stores are NON-TEMPORAL (bypass/evict-first in L2)
//    so the W[n] working set (~512 KB per XCD) stays L2-resident for B-reads
//  - B register pipeline deepened to 4 slots / depth 3 (12 x 16B in flight)
// -----------------------------------------------------------------------------
__global__ __launch_bounds__(256, 2) void gemm_k(
    const float* __restrict__ x, const int* __restrict__ idx,
    const unsigned short* __restrict__ wt, const float* __restrict__ bias,
    float* __restrict__ out)
{
    __shared__ __align__(16) unsigned short As[64 * 256];   // 32 KB bf16

    int bid = blockIdx.x;                  // 4096 blocks
    int L   = (bid & 7) * 512 + (bid >> 3);
    int n   = L >> 4;                      // 16 m-tiles of same n -> same XCD
    int mt  = L & 15;

    int tid  = threadIdx.x;
    int lane = tid & 63;
    int wv   = tid >> 6;
    int r16  = lane & 15;
    int q    = lane >> 4;

    const float*          xn = x  + (size_t)n * (BATCH * IN_SZ) + (size_t)mt * 64 * IN_SZ;
    const unsigned short* wq = wt + (size_t)n * WELEMS + q * 2048
                                  + (size_t)(wv * 64 + r16) * 8;

    auto loadB = [&](int ks, short8* dst) {
        #pragma unroll
        for (int nf = 0; nf < 4; ++nf)
            dst[nf] = *reinterpret_cast<const short8*>(
                wq + (size_t)ks * 8192 + nf * 128);
    };

    f32x4  acc[4][4] = {};
    short8 bf[4][4];                       // 4-slot B pipeline, depth 3

    // ---- stage x-tile: 64 rows x 256 f32 -> bf16 LDS, XOR swizzle ----
    // NON-TEMPORAL x reads: stream, don't thrash L2 (protect W lines)
    #pragma unroll
    for (int p = 0; p < 8; ++p) {
        int id    = p * 256 + tid;
        int row   = id >> 5;
        int chunk = id & 31;
        const float* gp = xn + (size_t)row * IN_SZ + chunk * 8;
        f32x4 v0 = __builtin_nontemporal_load(reinterpret_cast<const f32x4*>(gp));
        f32x4 v1 = __builtin_nontemporal_load(reinterpret_cast<const f32x4*>(gp) + 1);
        int off = row * 512 + ((chunk * 16) ^ ((row & 7) << 4));   // bytes
        *reinterpret_cast<short8*>(&As[off >> 1]) = cvt8(v0, v1);
    }
    // prefetch B for ks=0,1,2 (stay in flight across the barrier)
    loadB(0, bf[0]);
    loadB(1, bf[1]);
    loadB(2, bf[2]);
    __syncthreads();   // the only barrier

    #pragma unroll
    for (int ks = 0; ks < 8; ++ks) {
        // issue ks+3's loads first (slot (ks+3)%4 was consumed at ks-1)
        if (ks < 5) loadB(ks + 3, bf[(ks + 3) % 4]);
        short8 af[4];
        #pragma unroll
        for (int mf = 0; mf < 4; ++mf) {
            int row = mf * 16 + r16;
            int off = row * 512 + ((ks * 64 + q * 16) ^ ((row & 7) << 4));
            af[mf] = *reinterpret_cast<const short8*>(&As[off >> 1]);
        }
        const short8* bb = bf[ks % 4];
        #pragma unroll
        for (int mf = 0; mf < 4; ++mf)
            #pragma unroll
            for (int nf = 0; nf < 4; ++nf)
                acc[mf][nf] = __builtin_amdgcn_mfma_f32_16x16x32_bf16(
                    bb[nf], af[mf], acc[mf][nf], 0, 0, 0);   // swapped: out^T frag
    }

    // ---- epilogue: + bias, NON-TEMPORAL dwordx4 stores ----
    int c = idx[n];
    float* on = out + (size_t)n * (BATCH * OUT_SZ) + (size_t)mt * 64 * OUT_SZ;
    #pragma unroll
    for (int nf = 0; nf < 4; ++nf) {
        f32x4 bv = *reinterpret_cast<const f32x4*>(
            &bias[(size_t)c * OUT_SZ + wv * 64 + nf * 16 + q * 4]);
        #pragma unroll
        for (int mf = 0; mf < 4; ++mf) {
            f32x4 w = acc[mf][nf] + bv;
            __builtin_nontemporal_store(w, reinterpret_cast<f32x4*>(
                &on[(size_t)(mf * 16 + r16) * OUT_SZ + wv * 64 + nf * 16 + q * 4]));
        }
    }
}

extern "C" void kernel_launch(void* const* d_in, const int* in_sizes, int n_in,
                              void* d_out, int out_size, void* d_ws, size_t ws_size,
                              hipStream_t stream) {
    const float* x    = (const float*)d_in[0];
    const int*   idx  = (const int*)  d_in[1];
    const float* U    = (const float*)d_in[2];
    const float* V    = (const float*)d_in[3];
    const float* bias = (const float*)d_in[4];
    float* out = (float*)d_out;
    unsigned short* wt = (unsigned short*)d_ws;   // 32 MB scratch
    (void)in_sizes; (void)n_in; (void)out_size; (void)ws_size;

    synth_w<<<dim3(512),  dim3(256), 0, stream>>>(U, V, idx, wt);
    gemm_k <<<dim3(4096), dim3(256), 0, stream>>>(x, idx, wt, bias, out);
}